// Round 1
// baseline (56.813 us; speedup 1.0000x reference)
//
#include <hip/hip_runtime.h>

// B-spline activation (KAN-style), fp32.
// x: (8192, 1024) f32, coeff: (1024, 10) f32, out: (8192, 1024) f32.
// Uniform grid: linspace(-1,1,14), h = 2/13. Work in knot units u = (x+1)*6.5.
// Local De Boor: nonzero degree-3 bases are indices j-3..j, j = floor(u) in [0,12].
// Reference quirk: clamped x == 1.0 -> all degree-0 indicators zero -> out = 0.

constexpr int IN_FEATURES = 1024;
constexpr int N_BASES = 10;

__global__ __launch_bounds__(256) void bspline_act_kernel(
    const float* __restrict__ x,
    const float* __restrict__ coeff,
    float* __restrict__ out,
    int n4)
{
    const int stride = gridDim.x * blockDim.x;
    for (int i = blockIdx.x * blockDim.x + threadIdx.x; i < n4; i += stride) {
        const float4 xv = reinterpret_cast<const float4*>(x)[i];
        const int f0 = (i << 2) & (IN_FEATURES - 1);  // feature of first elem (4 | 1024, never crosses row)
        float xs[4] = {xv.x, xv.y, xv.z, xv.w};
        float r[4];
        #pragma unroll
        for (int e = 0; e < 4; ++e) {
            const float xc = fminf(fmaxf(xs[e], -1.0f), 1.0f);
            const float u = (xc + 1.0f) * 6.5f;
            int j = (int)u;              // u >= 0, truncation == floor
            j = j > 12 ? 12 : j;
            const float uj = u - (float)j;   // in [0,1] (==1 only in clamped top edge, masked below)

            // Cox–de Boor, uniform knots (denominators k, exact):
            // degree 1
            float N0 = 1.0f - uj;
            float N1 = uj;
            // degree 2
            {
                const float t0 = N0 * 0.5f, t1 = N1 * 0.5f;
                N0 = (1.0f - uj) * t0;
                const float n1 = (uj + 1.0f) * t0 + (2.0f - uj) * t1;
                const float n2 = uj * t1;
                N1 = n1;
                // N2 carried below
                const float inv3 = 0.3333333333333333f;
                // degree 3
                const float s0 = N0 * inv3, s1 = N1 * inv3, s2 = n2 * inv3;
                N0 = (1.0f - uj) * s0;
                N1 = (uj + 2.0f) * s0 + (2.0f - uj) * s1;
                const float N2 = (uj + 1.0f) * s1 + (3.0f - uj) * s2;
                const float N3 = uj * s2;

                // dot with coeff[f, j-3..j], branchless OOB masking
                const float* crow = coeff + (f0 + e) * N_BASES;
                const float Ns[4] = {N0, N1, N2, N3};
                float res = 0.0f;
                #pragma unroll
                for (int t = 0; t < 4; ++t) {
                    const int idx = j - 3 + t;
                    const int idxc = idx < 0 ? 0 : (idx > 9 ? 9 : idx);
                    const float m = (idx == idxc) ? 1.0f : 0.0f;
                    res = fmaf(Ns[t] * m, crow[idxc], res);
                }
                // reference: x clamped to exactly 1.0 has no degree-0 interval -> 0
                r[e] = (xc < 1.0f) ? res : 0.0f;
            }
        }
        const float4 ov = {r[0], r[1], r[2], r[3]};
        reinterpret_cast<float4*>(out)[i] = ov;
    }
}

extern "C" void kernel_launch(void* const* d_in, const int* in_sizes, int n_in,
                              void* d_out, int out_size, void* d_ws, size_t ws_size,
                              hipStream_t stream) {
    const float* x = (const float*)d_in[0];
    const float* coeff = (const float*)d_in[1];
    float* out = (float*)d_out;
    const int n4 = out_size / 4;   // 2,097,152 float4 groups
    const int threads = 256;
    const int blocks = 2048;       // grid-stride, ~4 iters/thread
    hipLaunchKernelGGL(bspline_act_kernel, dim3(blocks), dim3(threads), 0, stream,
                       x, coeff, out, n4);
}

// Round 2
// 21.059 us; speedup vs baseline: 2.6979x; 2.6979x over previous
//
#include <hip/hip_runtime.h>

// B-spline activation (KAN-style), fp32.
// x: (8192, 1024) f32, coeff: (1024, 10) f32, out: (8192, 1024) f32.
// Round-1 fix: coeff gathers moved from global (64-line TA serialization per
// wave ~= 55us) to LDS with stride-11 padding (gcd(11,32)=1 -> conflict-free).
// Lane == feature offset so x loads/stores are coalesced scalars.

constexpr int NB = 10;            // N_BASES
constexpr int ROWSTRIDE = 11;     // LDS row stride in floats (conflict-free)
constexpr int THREADS = 256;
constexpr int GRID = 2048;
constexpr int CHUNK = 512;        // elements per block per iteration
constexpr int TOTAL = 8192 * 1024;

__global__ __launch_bounds__(THREADS) void bspline_act_kernel(
    const float* __restrict__ x,
    const float* __restrict__ coeff,
    float* __restrict__ out)
{
    __shared__ float lds[CHUNK * ROWSTRIDE];   // 512 rows x 11 floats = 22.5 KB
    const int t = threadIdx.x;
    const int b = blockIdx.x;
    // base % 1024 is invariant across the k-loop (GRID*CHUNK % 1024 == 0)
    const int fbase = (b * CHUNK) & 1023;      // 0 or 512

    // Stage 512 coeff rows; thread t owns rows t and t+256.
    // Writes: lane stride 11 across banks -> conflict-free.
    #pragma unroll
    for (int rr = 0; rr < 2; ++rr) {
        const int r = t + rr * 256;
        const float* src = coeff + (fbase + r) * NB;   // 40B rows, 8B-aligned
        float v[NB];
        #pragma unroll
        for (int c = 0; c < 5; ++c) {
            const float2 p = reinterpret_cast<const float2*>(src)[c];
            v[2 * c] = p.x;
            v[2 * c + 1] = p.y;
        }
        #pragma unroll
        for (int c = 0; c < NB; ++c)
            lds[r * ROWSTRIDE + c] = v[c];
    }
    __syncthreads();

    #pragma unroll
    for (int k = 0; k < TOTAL / (GRID * CHUNK); ++k) {      // 8 iterations
        const int base = (b + k * GRID) * CHUNK;
        #pragma unroll
        for (int half = 0; half < 2; ++half) {
            const int s = t + half * 256;                   // feature-local row, 0..511
            const int E = base + s;
            const float xv = x[E];

            const float xc = fminf(fmaxf(xv, -1.0f), 1.0f);
            const float u = (xc + 1.0f) * 6.5f;             // knot units, [0,13]
            int j = (int)u;
            j = j > 12 ? 12 : j;
            const float tt = u - (float)j;                  // [0,1)

            // Local De Boor, uniform knots (denominators 1,2,3 exact).
            const float a0 = 1.0f - tt;
            const float h0 = a0 * 0.5f, h1 = tt * 0.5f;
            const float q0 = a0 * h0;
            const float q1 = (tt + 1.0f) * h0 + (2.0f - tt) * h1;
            const float q2 = tt * h1;
            constexpr float inv3 = 1.0f / 3.0f;
            const float s0 = q0 * inv3, s1 = q1 * inv3, s2 = q2 * inv3;
            float Ns[4];
            Ns[0] = a0 * s0;
            Ns[1] = (tt + 2.0f) * s0 + (2.0f - tt) * s1;
            Ns[2] = (tt + 1.0f) * s1 + (3.0f - tt) * s2;
            Ns[3] = tt * s2;

            // Dot with coeff[f, j-3..j] from LDS; branchless OOB masking.
            const float* crow = lds + s * ROWSTRIDE;
            float res = 0.0f;
            #pragma unroll
            for (int tp = 0; tp < 4; ++tp) {
                const int idx = j - 3 + tp;
                const int idxc = idx < 0 ? 0 : (idx > 9 ? 9 : idx);
                const float m = (idx == idxc) ? 1.0f : 0.0f;
                res = fmaf(Ns[tp] * m, crow[idxc], res);
            }
            // reference: x clamped to exactly 1.0 -> all degree-0 indicators 0
            out[E] = (xc < 1.0f) ? res : 0.0f;
        }
    }
}

extern "C" void kernel_launch(void* const* d_in, const int* in_sizes, int n_in,
                              void* d_out, int out_size, void* d_ws, size_t ws_size,
                              hipStream_t stream) {
    const float* x = (const float*)d_in[0];
    const float* coeff = (const float*)d_in[1];
    float* out = (float*)d_out;
    hipLaunchKernelGGL(bspline_act_kernel, dim3(GRID), dim3(THREADS), 0, stream,
                       x, coeff, out);
}

// Round 3
// 18.998 us; speedup vs baseline: 2.9905x; 1.1085x over previous
//
#include <hip/hip_runtime.h>

// B-spline activation (KAN-style), fp32.
// x: (8192, 1024) f32, coeff: (1024, 10) f32, out: (8192, 1024) f32.
// Round-2: zero-padded LDS rows (no tap masking, no edge select), closed-form
// cardinal cubic basis (Horner), contiguous taps (-> ds_read2_b32 merge),
// CHUNK=256 + stride-17 rows -> 17.4KB LDS -> 8 blocks/CU (full occupancy).

constexpr int NB = 10;           // N_BASES
constexpr int PAD = 3;
constexpr int ROWSTRIDE = 17;    // odd -> conflict-free base bank pattern
constexpr int THREADS = 256;
constexpr int GRID = 2048;
constexpr int CHUNK = 256;       // features per block (thread t <-> feature fbase+t)
constexpr int TOTAL = 8192 * 1024;
constexpr int ITERS = TOTAL / (GRID * CHUNK);   // 16

__global__ __launch_bounds__(THREADS) void bspline_act_kernel(
    const float* __restrict__ x,
    const float* __restrict__ coeff,
    float* __restrict__ out)
{
    __shared__ float lds[CHUNK * ROWSTRIDE];    // 256 rows x 17 floats = 17 KB
    const int t = threadIdx.x;
    const int b = blockIdx.x;
    const int fbase = (b & 3) * CHUNK;          // block's 256-feature panel

    // Zero the pad slots of row t (slots 0..2 and 13..15; basis n lives at n+3).
    {
        float* row = lds + t * ROWSTRIDE;
        row[0] = 0.0f; row[1] = 0.0f; row[2] = 0.0f;
        row[13] = 0.0f; row[14] = 0.0f; row[15] = 0.0f;
    }
    // Cooperative, coalesced stage of the 256x10 panel (2560 contiguous floats).
    const float* src = coeff + fbase * NB;
    #pragma unroll
    for (int it = 0; it < NB; ++it) {
        const int idx = t + it * THREADS;       // 0..2559
        const float v = src[idx];
        const int r = idx / NB;                 // magic-mul, no HW divide
        const int c = idx - r * NB;
        lds[r * ROWSTRIDE + PAD + c] = v;
    }
    __syncthreads();

    #pragma unroll
    for (int k = 0; k < ITERS; ++k) {
        const int E = (b + k * GRID) * CHUNK + t;   // coalesced: lane == feature
        const float xv = x[E];

        const float xc = fminf(fmaxf(xv, -1.0f), 1.0f);
        const float u = fmaf(xc, 6.5f, 6.5f);       // knot units, [0,13]
        const float jf = fminf(truncf(u), 12.0f);
        const float tt = u - jf;                    // [0,1]
        const int j = (int)jf;

        // Cardinal cubic B-spline values at local coord tt (partition of unity).
        const float t2 = tt * tt;
        const float a = 1.0f - tt;
        const float Ns0 = a * a * a * (1.0f / 6.0f);
        const float Ns3 = t2 * tt * (1.0f / 6.0f);
        const float p = fmaf(0.5f, tt, -1.0f);
        const float Ns1 = fmaf(p, t2, 2.0f / 3.0f); // 0.5t^3 - t^2 + 2/3
        const float Ns2 = 1.0f - Ns0 - Ns1 - Ns3;

        // Active bases j-3..j live at padded slots j..j+3: contiguous taps.
        const float* crow = lds + t * ROWSTRIDE + j;
        const float r0 = crow[0], r1 = crow[1], r2 = crow[2], r3 = crow[3];
        float res = Ns0 * r0;
        res = fmaf(Ns1, r1, res);
        res = fmaf(Ns2, r2, res);
        res = fmaf(Ns3, r3, res);
        // Edge x==+1 (u=13 -> j=12, tt=1): Ns0=0 and slots 13..15 are zero -> res=0,
        // matching the reference's empty degree-0 indicator at the top knot.
        out[E] = res;
    }
}

extern "C" void kernel_launch(void* const* d_in, const int* in_sizes, int n_in,
                              void* d_out, int out_size, void* d_ws, size_t ws_size,
                              hipStream_t stream) {
    const float* x = (const float*)d_in[0];
    const float* coeff = (const float*)d_in[1];
    float* out = (float*)d_out;
    hipLaunchKernelGGL(bspline_act_kernel, dim3(GRID), dim3(THREADS), 0, stream,
                       x, coeff, out);
}

// Round 4
// 16.318 us; speedup vs baseline: 3.4817x; 1.1642x over previous
//
#include <hip/hip_runtime.h>

// B-spline activation (KAN-style), fp32.
// x: (8192, 1024) f32, coeff: (1024, 10) f32, out: (8192, 1024) f32.
// Round-3: float4 global loads/stores (4 consecutive features per thread).
// LDS rows bit-swizzled (local row r -> phys ((r&3)<<6)|(r>>2)) so a thread's
// 4 rows sit 64 apart: per-tap bank pattern = 17*lane -> 2 lanes/bank (free).
// Zero-padded rows keep taps unmasked and make x==+/-1 exact-zero like the ref.

constexpr int NB = 10;           // N_BASES
constexpr int PAD = 3;
constexpr int RS = 17;           // LDS row stride (floats), odd -> conflict-free
constexpr int THREADS = 256;
constexpr int GRID = 2048;
constexpr int ITERS = 4;         // 2048 blocks * 4 iters * 4096 elems = 2^23

__global__ __launch_bounds__(THREADS) void bspline_act_kernel(
    const float* __restrict__ x,
    const float* __restrict__ coeff,
    float* __restrict__ out)
{
    __shared__ float lds[256 * RS];           // 17 KB -> 8 blocks/CU
    const int t = threadIdx.x;
    const int b = blockIdx.x;
    const int panel = b & 3;                  // 256-feature panel
    const int rg = b >> 2;                    // row-group id, 0..511
    const int fg = t & 63;                    // feature group (4 features)
    const int wr = t >> 6;                    // batch-row offset within group

    // Zero the pad slots of physical row t (slots 0..2, 13..15).
    {
        float* row = lds + t * RS;
        row[0] = 0.0f; row[1] = 0.0f; row[2] = 0.0f;
        row[13] = 0.0f; row[14] = 0.0f; row[15] = 0.0f;
    }
    // Stage the 256x10 coeff panel, coalesced; swizzled row placement.
    const float* src = coeff + panel * 256 * NB;
    #pragma unroll
    for (int it = 0; it < NB; ++it) {
        const int idx = t + it * THREADS;     // 0..2559
        const float v = src[idx];
        const int r = idx / NB;               // magic-mul
        const int c = idx - r * NB;
        const int phys = ((r & 3) << 6) | (r >> 2);
        lds[phys * RS + PAD + c] = v;
    }
    __syncthreads();

    const int base17 = fg * RS;

    #pragma unroll
    for (int k = 0; k < ITERS; ++k) {
        const int row = 4 * (rg + k * 512) + wr;          // batch row
        const int E4 = row * 256 + panel * 64 + fg;       // float4 index
        const float4 xv = reinterpret_cast<const float4*>(x)[E4];

        const float xs[4] = {xv.x, xv.y, xv.z, xv.w};
        float r[4];
        #pragma unroll
        for (int e = 0; e < 4; ++e) {
            const float xc = fminf(fmaxf(xs[e], -1.0f), 1.0f);
            const float u = fmaf(xc, 6.5f, 6.5f);         // knot units [0,13]
            const float jf = fminf(truncf(u), 12.0f);
            const float tt = u - jf;                      // [0,1]
            const int j = (int)jf;

            // Cardinal cubic B-spline weights (partition of unity).
            const float t2 = tt * tt;
            const float a = 1.0f - tt;
            const float Ns0 = a * a * a * (1.0f / 6.0f);
            const float Ns3 = t2 * tt * (1.0f / 6.0f);
            const float p = fmaf(0.5f, tt, -1.0f);
            const float Ns1 = fmaf(p, t2, 2.0f / 3.0f);
            const float Ns2 = 1.0f - Ns0 - Ns1 - Ns3;

            // Element e reads physical row (e<<6)|fg; taps at slots j..j+3.
            const float* crow = lds + (e * 64 * RS) + base17 + j;
            float res = Ns0 * crow[0];
            res = fmaf(Ns1, crow[1], res);
            res = fmaf(Ns2, crow[2], res);
            res = fmaf(Ns3, crow[3], res);
            r[e] = res;   // x==+1: j=12, Ns0=0, slots 13..15 zero -> 0 (ref quirk)
        }
        const float4 ov = {r[0], r[1], r[2], r[3]};
        reinterpret_cast<float4*>(out)[E4] = ov;
    }
}

extern "C" void kernel_launch(void* const* d_in, const int* in_sizes, int n_in,
                              void* d_out, int out_size, void* d_ws, size_t ws_size,
                              hipStream_t stream) {
    const float* x = (const float*)d_in[0];
    const float* coeff = (const float*)d_in[1];
    float* out = (float*)d_out;
    hipLaunchKernelGGL(bspline_act_kernel, dim3(GRID), dim3(THREADS), 0, stream,
                       x, coeff, out);
}